// Round 15
// baseline (9088.539 us; speedup 1.0000x reference)
//
#include <hip/hip_runtime.h>
#include <math.h>

#define NL 24
#define NB 64
#define TPB 1024
#define QROWS 765
// ---- ws layout (float units) ----
#define RING_F  3133440                    // [64][765][64]
#define MB_OFF  RING_F                     // M matrices: [24][64][128]
#define CB2_OFF (MB_OFF + 24*64*128)       // folded conv bias: [24][128]
#define CV_OFF  (CB2_OFF + 24*128)         // conv pack: 24*6*1024 f4
#define RS_OFF  (CV_OFF + 24*6*1024*4)     // res+skip pack: 24*5*1024 f4
#define PH_OFF  (RS_OFF + 24*5*1024*4)     // head pack: 2*16*1024 f4

typedef float vf4 __attribute__((ext_vector_type(4)));

struct WBc  { float4 v[6]; };   // conv 3-term frag (24 VGPR) — double-buffered
struct WBrs { float4 v[5]; };   // res+skip frag (20 VGPR) — single, per-phase

__device__ __forceinline__ float hadd4(float4 v) { return (v.x + v.y) + (v.z + v.w); }
__device__ __forceinline__ void fma4(float4& a, float4 x, float4 w) {
    a.x = fmaf(x.x, w.x, a.x); a.y = fmaf(x.y, w.y, a.y);
    a.z = fmaf(x.z, w.z, a.z); a.w = fmaf(x.w, w.w, a.w);
}
// barrier WITHOUT vmcnt drain (prefetches stay in flight)
__device__ __forceinline__ void bar() {
    asm volatile("s_waitcnt lgkmcnt(0)" ::: "memory");
    __builtin_amdgcn_s_barrier();
    asm volatile("" ::: "memory");
}
__device__ __forceinline__ void pf_cv(WBc& b, const float4* __restrict__ cvp, int layer, int tid) {
    const float4* p = cvp + (size_t)layer * (6 * 1024) + tid;
#pragma unroll
    for (int j = 0; j < 6; ++j) b.v[j] = p[j * 1024];
}
__device__ __forceinline__ void pf_rs(WBrs& b, const float4* __restrict__ rsp, int layer, int tid) {
    const float4* p = rsp + (size_t)layer * (5 * 1024) + tid;
#pragma unroll
    for (int j = 0; j < 5; ++j) b.v[j] = p[j * 1024];
}

// ---------------- repack1: M_i = R_{i-1} @ K1_i ; cb2_i = cb_i + rb_{i-1} @ K1_i ----------------
__global__ void repack1(const float* __restrict__ conv_k, const float* __restrict__ res_w,
                        const float* __restrict__ conv_b, const float* __restrict__ res_b,
                        float* __restrict__ ws) {
    const int i = blockIdx.x, col = threadIdx.x;   // 24 x 128
    float* M   = ws + MB_OFF;
    float* cb2 = ws + CB2_OFF;
    if (i == 0) {
        for (int m = 0; m < 64; ++m) M[(size_t)m * 128 + col] = 0.f;
        cb2[col] = conv_b[col];
        return;
    }
    float k1[64];
#pragma unroll
    for (int k = 0; k < 64; ++k)
        k1[k] = conv_k[((size_t)(i * 2 + 1) * 64 + k) * 128 + col];
    for (int m = 0; m < 64; ++m) {
        float a = 0.f;
#pragma unroll
        for (int k = 0; k < 64; ++k)
            a = fmaf(res_w[((size_t)(i - 1) * 64 + m) * 64 + k], k1[k], a);
        M[((size_t)i * 64 + m) * 128 + col] = a;
    }
    float cb = conv_b[i * 128 + col];
#pragma unroll
    for (int k = 0; k < 64; ++k)
        cb = fmaf(res_b[(i - 1) * 64 + k], k1[k], cb);
    cb2[i * 128 + col] = cb;
}

// ---------------- repack2: lane-major packs for 1024-thread decomposition ----------------
__global__ void repack2(const float* __restrict__ conv_k, const float* __restrict__ res_w,
                        const float* __restrict__ skip_w, const float* __restrict__ out0_w,
                        const float* __restrict__ out1_w, float* __restrict__ ws) {
    const int bb = blockIdx.x, tid = threadIdx.x;
    float4* CV = (float4*)(ws + CV_OFF);
    float4* RS = (float4*)(ws + RS_OFF);
    float4* PH = (float4*)(ws + PH_OFF);
    const float* M = ws + MB_OFF;
    if (bb < NL) {
        const int i  = bb;
        const int p  = tid >> 4;          // conv/res column pair base (0..63)
        const int kk = (tid & 15) * 4;    // conv/res K-chunk
        float4* dst = CV + (size_t)i * (6 * 1024) + tid;
#pragma unroll
        for (int half = 0; half < 2; ++half) {
            const int cc = p + half * 64;
            float4 a, b, m;
            a.x = conv_k[((size_t)(i * 2 + 0) * 64 + kk + 0) * 128 + cc];
            a.y = conv_k[((size_t)(i * 2 + 0) * 64 + kk + 1) * 128 + cc];
            a.z = conv_k[((size_t)(i * 2 + 0) * 64 + kk + 2) * 128 + cc];
            a.w = conv_k[((size_t)(i * 2 + 0) * 64 + kk + 3) * 128 + cc];
            b.x = conv_k[((size_t)(i * 2 + 1) * 64 + kk + 0) * 128 + cc];
            b.y = conv_k[((size_t)(i * 2 + 1) * 64 + kk + 1) * 128 + cc];
            b.z = conv_k[((size_t)(i * 2 + 1) * 64 + kk + 2) * 128 + cc];
            b.w = conv_k[((size_t)(i * 2 + 1) * 64 + kk + 3) * 128 + cc];
            m.x = M[((size_t)i * 64 + kk + 0) * 128 + cc];
            m.y = M[((size_t)i * 64 + kk + 1) * 128 + cc];
            m.z = M[((size_t)i * 64 + kk + 2) * 128 + cc];
            m.w = M[((size_t)i * 64 + kk + 3) * 128 + cc];
            dst[(0 + half) * 1024] = a;       // v[0],v[1]: K0 cols p, p+64
            dst[(2 + half) * 1024] = b;       // v[2],v[3]: K1
            dst[(4 + half) * 1024] = m;       // v[4],v[5]: M
        }
        float4* rdst = RS + (size_t)i * (5 * 1024) + tid;
        {
            float4 v;                          // v[0]: res col p, rows kk..kk+3
            v.x = res_w[((size_t)i * 64 + kk + 0) * 64 + p];
            v.y = res_w[((size_t)i * 64 + kk + 1) * 64 + p];
            v.z = res_w[((size_t)i * 64 + kk + 2) * 64 + p];
            v.w = res_w[((size_t)i * 64 + kk + 3) * 64 + p];
            rdst[0] = v;
        }
        const int s  = tid >> 2;          // skip col (0..255)
        const int ks = (tid & 3) * 16;    // skip K-chunk
#pragma unroll
        for (int jj = 0; jj < 4; ++jj) {
            float4 v; const int k0 = ks + jj * 4;
            v.x = skip_w[((size_t)i * 64 + k0 + 0) * 256 + s];
            v.y = skip_w[((size_t)i * 64 + k0 + 1) * 256 + s];
            v.z = skip_w[((size_t)i * 64 + k0 + 2) * 256 + s];
            v.w = skip_w[((size_t)i * 64 + k0 + 3) * 256 + s];
            rdst[(1 + jj) * 1024] = v;
        }
    } else {
        const int which = bb - NL;            // 0: out0_w, 1: out1_w
        const float* W = which ? out1_w : out0_w;
        float4* dst = PH + (size_t)which * (16 * 1024) + tid;
        const int c2 = tid >> 2;
        const int kb = (tid & 3) * 64;
        for (int j = 0; j < 16; ++j) {
            float4 v; const int k0 = kb + j * 4;
            v.x = W[(size_t)(k0 + 0) * 256 + c2];
            v.y = W[(size_t)(k0 + 1) * 256 + c2];
            v.z = W[(size_t)(k0 + 2) * 256 + c2];
            v.w = W[(size_t)(k0 + 3) * 256 + c2];
            dst[j * 1024] = v;
        }
    }
}

// ---------------- main generator: 1024 threads (16 waves), one phase per layer ----------------
__global__ __launch_bounds__(TPB)
void wavenet_gen(const int* __restrict__ seed,
                 const float* __restrict__ embed,
                 const float* __restrict__ res_b,
                 const float* __restrict__ skip_b,
                 const float* __restrict__ out0_b,
                 const float* __restrict__ out1_b,
                 const int* __restrict__ Tptr,
                 float* __restrict__ out,
                 float* __restrict__ ring,
                 const float4* __restrict__ cvp,
                 const float4* __restrict__ rsp,
                 const float4* __restrict__ php,
                 const float* __restrict__ cb2p)
{
    const int b   = blockIdx.x;
    const int tid = threadIdx.x;
    const int w   = tid >> 6;
    const int l   = tid & 63;
    const int T   = *Tptr;

    __shared__ __align__(16) float xl[2][64];        // xlast ping-pong
    __shared__ __align__(16) float yb[2][64];        // layer-input ping-pong
    __shared__ __align__(16) float gb[2][64];        // gate ping-pong
    __shared__ __align__(16) float skl[256];
    __shared__ __align__(16) float h0l[256];
    __shared__ __align__(16) float ebt[256 * 64];
    __shared__ __align__(16) float cb2S[NL * 128];
    __shared__ __align__(16) float rbS[NL * 64];
    __shared__ __align__(16) float o0bS[256], o1bS[256], sbtS[256];
    __shared__ float wmaxv[16];
    __shared__ int   wmaxi[16];

    float* q = ring + (size_t)b * (QROWS * 64);

    // ---- init ----
    {
        vf4* q4 = (vf4*)q;
        const vf4 z = (vf4){0.f, 0.f, 0.f, 0.f};
        for (int idx = tid; idx < QROWS * 64 / 4; idx += TPB)
            __builtin_nontemporal_store(z, &q4[idx]);
        const float4* s4; float4* d4;
        s4 = (const float4*)embed;  d4 = (float4*)ebt;
        for (int idx = tid; idx < 256 * 64 / 4; idx += TPB) d4[idx] = s4[idx];
        s4 = (const float4*)cb2p;   d4 = (float4*)cb2S;
        for (int idx = tid; idx < NL * 128 / 4; idx += TPB) d4[idx] = s4[idx];
        s4 = (const float4*)res_b;  d4 = (float4*)rbS;
        for (int idx = tid; idx < NL * 64 / 4; idx += TPB) d4[idx] = s4[idx];
        s4 = (const float4*)out0_b; d4 = (float4*)o0bS;
        for (int idx = tid; idx < 64; idx += TPB) d4[idx] = s4[idx];
        s4 = (const float4*)out1_b; d4 = (float4*)o1bS;
        for (int idx = tid; idx < 64; idx += TPB) d4[idx] = s4[idx];
        if (tid < 256) {
            float acc = 0.f;
            for (int i = 0; i < NL; ++i) acc += skip_b[i * 256 + tid];
            sbtS[tid] = acc;
        }
    }
    __syncthreads();
    if (tid < 64) {
        const int smp = seed[b];
        yb[0][tid] = ebt[smp * 64 + tid];   // x_0(t=0) = embed[seed]
        yb[1][tid] = 0.f;
        xl[0][tid] = 0.f;
        xl[1][tid] = 0.f;
        gb[0][tid] = 0.f;                   // avoid NaN*0 in layer-0 M-term
        gb[1][tid] = 0.f;
    }
    __syncthreads();

    WBc  CVa, CVb;
    WBrs RS;
    pf_cv(CVa, cvp, 0, tid);

    float* out_pred = out + (size_t)b * T;
    float* out_log  = out + (size_t)NB * T + (size_t)b * T * 256;

    const int p   = tid >> 4;          // conv/res column (0..63); second col p+64
    const int kk  = (tid & 15) * 4;    // conv/res K-chunk
    const int s   = tid >> 2;          // skip / head column (0..255)
    const int ks  = (tid & 3) * 16;    // skip K-chunk
    const int kb2 = (tid & 3) * 64;    // head K-chunk

    float skv = 0.f;

    for (int t = 0; t < T; ++t) {

        auto phase = [&](WBc& cur, WBc& nxt, const int i) {
            const int j = (i + 1 < NL) ? (i + 1) : 0;
            // ---- issue: ring read, RS_{i-1}, CV_j, ring push ----
            float xln = 0.f;
            if (w == 15) {
                const int dj = 1 << (j & 7);
                const int st = (i == NL - 1) ? (t + 1) : t;
                const int row = 255 * (j >> 3) + (dj - 1) + (st & (dj - 1));
                xln = __builtin_nontemporal_load(&q[(size_t)row * 64 + l]);
            }
            if (i) pf_rs(RS, rsp, i - 1, tid);
            pf_cv(nxt, cvp, j, tid);
            if (w == 14 && i) {             // push x_{i-1}(t) into layer-(i-1) ring row
                const int dp = 1 << ((i - 1) & 7);
                const int row = 255 * ((i - 1) >> 3) + (dp - 1) + (t & (dp - 1));
                __builtin_nontemporal_store(yb[(i - 1) & 1][l], &q[(size_t)row * 64 + l]);
            }
            const int ybi = i ? ((i - 1) & 1) : 0;   // buffer holding x_{i-1} (x_0 for i=0)
            const int gbi = (i - 1) & 1;             // buffer holding g_{i-1} (x*0 for i=0)
            // ---- 3-term conv (uses cur, loaded a full phase ago) ----
            const float4 xlv = *(const float4*)&xl[i & 1][kk];
            const float4 ypv = *(const float4*)&yb[ybi][kk];
            const float4 gpv = *(const float4*)&gb[gbi][kk];
            float4 aA = make_float4(0.f, 0.f, 0.f, 0.f);
            float4 aB = make_float4(0.f, 0.f, 0.f, 0.f);
            fma4(aA, xlv, cur.v[0]); fma4(aA, ypv, cur.v[2]); fma4(aA, gpv, cur.v[4]);
            fma4(aB, xlv, cur.v[1]); fma4(aB, ypv, cur.v[3]); fma4(aB, gpv, cur.v[5]);
            float hA = hadd4(aA), hB = hadd4(aB);
            hA += __shfl_xor(hA, 1);  hB += __shfl_xor(hB, 1);
            hA += __shfl_xor(hA, 2);  hB += __shfl_xor(hB, 2);
            hA += __shfl_xor(hA, 4);  hB += __shfl_xor(hB, 4);
            hA += __shfl_xor(hA, 8);  hB += __shfl_xor(hB, 8);
            hA += cb2S[i * 128 + p];
            hB += cb2S[i * 128 + 64 + p];
            const float g = tanhf(hA) * (1.f / (1.f + expf(-hB)));
            // ---- deferred res + skip of layer i-1 ----
            float ynew = 0.f;
            if (i) {
                float4 ra = make_float4(0.f, 0.f, 0.f, 0.f);
                fma4(ra, gpv, RS.v[0]);
                float racc = hadd4(ra);
                racc += __shfl_xor(racc, 1);
                racc += __shfl_xor(racc, 2);
                racc += __shfl_xor(racc, 4);
                racc += __shfl_xor(racc, 8);
                ynew = yb[ybi][p] + racc + rbS[(i - 1) * 64 + p];
                const float4 gs0 = *(const float4*)&gb[gbi][ks];
                const float4 gs1 = *(const float4*)&gb[gbi][ks + 4];
                const float4 gs2 = *(const float4*)&gb[gbi][ks + 8];
                const float4 gs3 = *(const float4*)&gb[gbi][ks + 12];
                float4 sa = make_float4(0.f, 0.f, 0.f, 0.f);
                fma4(sa, gs0, RS.v[1]); fma4(sa, gs1, RS.v[2]);
                fma4(sa, gs2, RS.v[3]); fma4(sa, gs3, RS.v[4]);
                float ss = hadd4(sa);
                ss += __shfl_xor(ss, 1);
                ss += __shfl_xor(ss, 2);
                skv += ss;
            }
            // ---- publish ----
            if ((tid & 15) == 0) {
                gb[i & 1][p] = g;
                if (i) yb[i & 1][p] = ynew;
            }
            if (w == 15) xl[j & 1][l] = xln;
            bar();
        };

#pragma unroll 1
        for (int ii = 0; ii < NL; ii += 2) {
            phase(CVa, CVb, ii);
            phase(CVb, CVa, ii + 1);
        }

        // ---------------- head A: skip_23, finalize skl, push row(23) ----------------
        {
            pf_rs(RS, rsp, NL - 1, tid);
            const float4 gs0 = *(const float4*)&gb[1][ks];
            const float4 gs1 = *(const float4*)&gb[1][ks + 4];
            const float4 gs2 = *(const float4*)&gb[1][ks + 8];
            const float4 gs3 = *(const float4*)&gb[1][ks + 12];
            float4 sa = make_float4(0.f, 0.f, 0.f, 0.f);
            fma4(sa, gs0, RS.v[1]); fma4(sa, gs1, RS.v[2]);
            fma4(sa, gs2, RS.v[3]); fma4(sa, gs3, RS.v[4]);
            float ss = hadd4(sa);
            ss += __shfl_xor(ss, 1);
            ss += __shfl_xor(ss, 2);
            skv += ss;
            if ((tid & 3) == 0) skl[s] = skv + sbtS[s];
            skv = 0.f;
            if (w == 14) {                  // push x_23(t) into layer-23 ring row
                const int row = 510 + 127 + (t & 127);
                __builtin_nontemporal_store(yb[1][l], &q[(size_t)row * 64 + l]);
            }
            bar();
        }
        // ---------------- head B: GEMV1 ----------------
        {
            const float4* hp = php + tid;
            float4 ha = make_float4(0.f, 0.f, 0.f, 0.f);
#pragma unroll
            for (int jj = 0; jj < 16; ++jj) {
                const float4 wv = hp[jj * 1024];
                const float4 sv = *(const float4*)&skl[kb2 + jj * 4];
                fma4(ha, sv, wv);
            }
            float hs = hadd4(ha);
            hs += __shfl_xor(hs, 1);
            hs += __shfl_xor(hs, 2);
            const float h0 = fmaxf(hs + o0bS[s], 0.f);
            if ((tid & 3) == 0) h0l[s] = h0;
        }
        bar();
        // ---------------- head C: GEMV2 + wave argmax ----------------
        {
            const float4* hp = php + (16 * 1024) + tid;
            float4 la = make_float4(0.f, 0.f, 0.f, 0.f);
#pragma unroll
            for (int jj = 0; jj < 16; ++jj) {
                const float4 wv = hp[jj * 1024];
                const float4 hv = *(const float4*)&h0l[kb2 + jj * 4];
                fma4(la, hv, wv);
            }
            float ls = hadd4(la);
            ls += __shfl_xor(ls, 1);
            ls += __shfl_xor(ls, 2);
            const float logit = ls + o1bS[s];
            if ((tid & 3) == 0)
                __builtin_nontemporal_store(logit, &out_log[(size_t)t * 256 + s]);
            float bv = logit; int bi = s;
#pragma unroll
            for (int off = 1; off <= 32; off <<= 1) {
                const float ov = __shfl_xor(bv, off);
                const int   oi = __shfl_xor(bi, off);
                if (ov > bv || (ov == bv && oi < bi)) { bv = ov; bi = oi; }
            }
            if (l == 0) { wmaxv[w] = bv; wmaxi[w] = bi; }
        }
        bar();
        // ---------------- head D: final argmax, x_0(t+1), mu-law ----------------
        {
            float fv = wmaxv[0]; int fi = wmaxi[0];
#pragma unroll
            for (int ww = 1; ww < 16; ++ww) {
                const float vv = wmaxv[ww]; const int vi = wmaxi[ww];
                if (vv > fv || (vv == fv && vi < fi)) { fv = vv; fi = vi; }
            }
            if (tid < 64) yb[0][tid] = ebt[fi * 64 + tid];   // x_0 of next step
            if (tid == 0) {
                const float mw = (float)fi * (2.0f / 255.0f) - 1.0f;
                const float a  = fabsf(mw);
                const float pp = (exp2f(8.0f * a) - 1.0f) * (1.0f / 255.0f);
                __builtin_nontemporal_store((mw < 0.f) ? -pp : pp, &out_pred[t]);
            }
        }
        bar();
    }
}

extern "C" void kernel_launch(void* const* d_in, const int* in_sizes, int n_in,
                              void* d_out, int out_size, void* d_ws, size_t ws_size,
                              hipStream_t stream) {
    const int*   seed   = (const int*)  d_in[0];
    const float* embed  = (const float*)d_in[1];
    const float* conv_k = (const float*)d_in[2];
    const float* conv_b = (const float*)d_in[3];
    const float* res_w  = (const float*)d_in[4];
    const float* res_b  = (const float*)d_in[5];
    const float* skip_w = (const float*)d_in[6];
    const float* skip_b = (const float*)d_in[7];
    const float* out0_w = (const float*)d_in[8];
    const float* out0_b = (const float*)d_in[9];
    const float* out1_w = (const float*)d_in[10];
    const float* out1_b = (const float*)d_in[11];
    const int*   Tptr   = (const int*)  d_in[12];

    float* ws = (float*)d_ws;
    float* ring = ws;
    const float4* cvp  = (const float4*)(ws + CV_OFF);
    const float4* rsp  = (const float4*)(ws + RS_OFF);
    const float4* php  = (const float4*)(ws + PH_OFF);
    const float*  cb2p = ws + CB2_OFF;

    repack1<<<dim3(NL), dim3(128), 0, stream>>>(conv_k, res_w, conv_b, res_b, ws);
    repack2<<<dim3(NL + 2), dim3(1024), 0, stream>>>(conv_k, res_w, skip_w, out0_w, out1_w, ws);

    wavenet_gen<<<dim3(NB), dim3(TPB), 0, stream>>>(
        seed, embed, res_b, skip_b, out0_b, out1_b, Tptr,
        (float*)d_out, ring, cvp, rsp, php, cb2p);
}

// Round 16
// 9085.036 us; speedup vs baseline: 1.0004x; 1.0004x over previous
//
#include <hip/hip_runtime.h>
#include <math.h>

#define NL 24
#define NB 64
#define TPB 1024
#define QROWS 765
// ---- ws layout (float units) ----
#define RING_F  3133440                    // [64][765][64]
#define MB_OFF  RING_F                     // M matrices: [24][64][128]
#define CB2_OFF (MB_OFF + 24*64*128)       // folded conv bias: [24][128]
#define CV_OFF  (CB2_OFF + 24*128)         // conv pack: 24*6*1024 f4
#define RS_OFF  (CV_OFF + 24*6*1024*4)     // res+skip pack: 24*5*1024 f4
#define PH_OFF  (RS_OFF + 24*5*1024*4)     // head pack: 2*16*1024 f4

typedef float vf4 __attribute__((ext_vector_type(4)));

struct WBc  { float4 v[6]; };   // conv 3-term frag (24 VGPR) — double-buffered
struct WBrs { float4 v[5]; };   // res+skip frag (20 VGPR) — single, per-phase

__device__ __forceinline__ float hadd4(float4 v) { return (v.x + v.y) + (v.z + v.w); }
__device__ __forceinline__ void fma4(float4& a, float4 x, float4 w) {
    a.x = fmaf(x.x, w.x, a.x); a.y = fmaf(x.y, w.y, a.y);
    a.z = fmaf(x.z, w.z, a.z); a.w = fmaf(x.w, w.w, a.w);
}
// barrier WITHOUT vmcnt drain (prefetches stay in flight)
__device__ __forceinline__ void bar() {
    asm volatile("s_waitcnt lgkmcnt(0)" ::: "memory");
    __builtin_amdgcn_s_barrier();
    asm volatile("" ::: "memory");
}
__device__ __forceinline__ void pf_cv(WBc& b, const float4* __restrict__ cvp, int layer, int tid) {
    const float4* p = cvp + (size_t)layer * (6 * 1024) + tid;
#pragma unroll
    for (int j = 0; j < 6; ++j) b.v[j] = p[j * 1024];
}
__device__ __forceinline__ void pf_rs(WBrs& b, const float4* __restrict__ rsp, int layer, int tid) {
    const float4* p = rsp + (size_t)layer * (5 * 1024) + tid;
#pragma unroll
    for (int j = 0; j < 5; ++j) b.v[j] = p[j * 1024];
}

// ---------------- repack1: M_i = R_{i-1} @ K1_i ; cb2_i = cb_i + rb_{i-1} @ K1_i ----------------
__global__ void repack1(const float* __restrict__ conv_k, const float* __restrict__ res_w,
                        const float* __restrict__ conv_b, const float* __restrict__ res_b,
                        float* __restrict__ ws) {
    const int i = blockIdx.x, col = threadIdx.x;   // 24 x 128
    float* M   = ws + MB_OFF;
    float* cb2 = ws + CB2_OFF;
    if (i == 0) {
        for (int m = 0; m < 64; ++m) M[(size_t)m * 128 + col] = 0.f;
        cb2[col] = conv_b[col];
        return;
    }
    float k1[64];
#pragma unroll
    for (int k = 0; k < 64; ++k)
        k1[k] = conv_k[((size_t)(i * 2 + 1) * 64 + k) * 128 + col];
    for (int m = 0; m < 64; ++m) {
        float a = 0.f;
#pragma unroll
        for (int k = 0; k < 64; ++k)
            a = fmaf(res_w[((size_t)(i - 1) * 64 + m) * 64 + k], k1[k], a);
        M[((size_t)i * 64 + m) * 128 + col] = a;
    }
    float cb = conv_b[i * 128 + col];
#pragma unroll
    for (int k = 0; k < 64; ++k)
        cb = fmaf(res_b[(i - 1) * 64 + k], k1[k], cb);
    cb2[i * 128 + col] = cb;
}

// ---------------- repack2: lane-major packs for 1024-thread decomposition ----------------
__global__ void repack2(const float* __restrict__ conv_k, const float* __restrict__ res_w,
                        const float* __restrict__ skip_w, const float* __restrict__ out0_w,
                        const float* __restrict__ out1_w, float* __restrict__ ws) {
    const int bb = blockIdx.x, tid = threadIdx.x;
    float4* CV = (float4*)(ws + CV_OFF);
    float4* RS = (float4*)(ws + RS_OFF);
    float4* PH = (float4*)(ws + PH_OFF);
    const float* M = ws + MB_OFF;
    if (bb < NL) {
        const int i  = bb;
        const int p  = tid >> 4;          // conv/res column pair base (0..63)
        const int kk = (tid & 15) * 4;    // conv/res K-chunk
        float4* dst = CV + (size_t)i * (6 * 1024) + tid;
#pragma unroll
        for (int half = 0; half < 2; ++half) {
            const int cc = p + half * 64;
            float4 a, b, m;
            a.x = conv_k[((size_t)(i * 2 + 0) * 64 + kk + 0) * 128 + cc];
            a.y = conv_k[((size_t)(i * 2 + 0) * 64 + kk + 1) * 128 + cc];
            a.z = conv_k[((size_t)(i * 2 + 0) * 64 + kk + 2) * 128 + cc];
            a.w = conv_k[((size_t)(i * 2 + 0) * 64 + kk + 3) * 128 + cc];
            b.x = conv_k[((size_t)(i * 2 + 1) * 64 + kk + 0) * 128 + cc];
            b.y = conv_k[((size_t)(i * 2 + 1) * 64 + kk + 1) * 128 + cc];
            b.z = conv_k[((size_t)(i * 2 + 1) * 64 + kk + 2) * 128 + cc];
            b.w = conv_k[((size_t)(i * 2 + 1) * 64 + kk + 3) * 128 + cc];
            m.x = M[((size_t)i * 64 + kk + 0) * 128 + cc];
            m.y = M[((size_t)i * 64 + kk + 1) * 128 + cc];
            m.z = M[((size_t)i * 64 + kk + 2) * 128 + cc];
            m.w = M[((size_t)i * 64 + kk + 3) * 128 + cc];
            dst[(0 + half) * 1024] = a;       // v[0],v[1]: K0 cols p, p+64
            dst[(2 + half) * 1024] = b;       // v[2],v[3]: K1
            dst[(4 + half) * 1024] = m;       // v[4],v[5]: M
        }
        float4* rdst = RS + (size_t)i * (5 * 1024) + tid;
        {
            float4 v;                          // v[0]: res col p, rows kk..kk+3
            v.x = res_w[((size_t)i * 64 + kk + 0) * 64 + p];
            v.y = res_w[((size_t)i * 64 + kk + 1) * 64 + p];
            v.z = res_w[((size_t)i * 64 + kk + 2) * 64 + p];
            v.w = res_w[((size_t)i * 64 + kk + 3) * 64 + p];
            rdst[0] = v;
        }
        const int s  = tid >> 2;          // skip col (0..255)
        const int ks = (tid & 3) * 16;    // skip K-chunk
#pragma unroll
        for (int jj = 0; jj < 4; ++jj) {
            float4 v; const int k0 = ks + jj * 4;
            v.x = skip_w[((size_t)i * 64 + k0 + 0) * 256 + s];
            v.y = skip_w[((size_t)i * 64 + k0 + 1) * 256 + s];
            v.z = skip_w[((size_t)i * 64 + k0 + 2) * 256 + s];
            v.w = skip_w[((size_t)i * 64 + k0 + 3) * 256 + s];
            rdst[(1 + jj) * 1024] = v;
        }
    } else {
        const int which = bb - NL;            // 0: out0_w, 1: out1_w
        const float* W = which ? out1_w : out0_w;
        float4* dst = PH + (size_t)which * (16 * 1024) + tid;
        const int c2 = tid >> 2;
        const int kb = (tid & 3) * 64;
        for (int j = 0; j < 16; ++j) {
            float4 v; const int k0 = kb + j * 4;
            v.x = W[(size_t)(k0 + 0) * 256 + c2];
            v.y = W[(size_t)(k0 + 1) * 256 + c2];
            v.z = W[(size_t)(k0 + 2) * 256 + c2];
            v.w = W[(size_t)(k0 + 3) * 256 + c2];
            dst[j * 1024] = v;
        }
    }
}

// ---------------- main generator: 1024 threads (16 waves = 4/EU), one phase per layer ----------------
// __launch_bounds__(1024, 4): min 4 waves/EU -> VGPR budget 512/4 = 128.
// (R15's plain __launch_bounds__(1024) defaulted to a 64-VGPR target -> ~35-reg spill, FETCH 3.8 GB.)
__global__ __launch_bounds__(TPB, 4)
void wavenet_gen(const int* __restrict__ seed,
                 const float* __restrict__ embed,
                 const float* __restrict__ res_b,
                 const float* __restrict__ skip_b,
                 const float* __restrict__ out0_b,
                 const float* __restrict__ out1_b,
                 const int* __restrict__ Tptr,
                 float* __restrict__ out,
                 float* __restrict__ ring,
                 const float4* __restrict__ cvp,
                 const float4* __restrict__ rsp,
                 const float4* __restrict__ php,
                 const float* __restrict__ cb2p)
{
    const int b   = blockIdx.x;
    const int tid = threadIdx.x;
    const int w   = tid >> 6;
    const int l   = tid & 63;
    const int T   = *Tptr;

    __shared__ __align__(16) float xl[2][64];        // xlast ping-pong
    __shared__ __align__(16) float yb[2][64];        // layer-input ping-pong
    __shared__ __align__(16) float gb[2][64];        // gate ping-pong
    __shared__ __align__(16) float skl[256];
    __shared__ __align__(16) float h0l[256];
    __shared__ __align__(16) float ebt[256 * 64];
    __shared__ __align__(16) float cb2S[NL * 128];
    __shared__ __align__(16) float rbS[NL * 64];
    __shared__ __align__(16) float o0bS[256], o1bS[256], sbtS[256];
    __shared__ float wmaxv[16];
    __shared__ int   wmaxi[16];

    float* q = ring + (size_t)b * (QROWS * 64);

    // ---- init ----
    {
        vf4* q4 = (vf4*)q;
        const vf4 z = (vf4){0.f, 0.f, 0.f, 0.f};
        for (int idx = tid; idx < QROWS * 64 / 4; idx += TPB)
            __builtin_nontemporal_store(z, &q4[idx]);
        const float4* s4; float4* d4;
        s4 = (const float4*)embed;  d4 = (float4*)ebt;
        for (int idx = tid; idx < 256 * 64 / 4; idx += TPB) d4[idx] = s4[idx];
        s4 = (const float4*)cb2p;   d4 = (float4*)cb2S;
        for (int idx = tid; idx < NL * 128 / 4; idx += TPB) d4[idx] = s4[idx];
        s4 = (const float4*)res_b;  d4 = (float4*)rbS;
        for (int idx = tid; idx < NL * 64 / 4; idx += TPB) d4[idx] = s4[idx];
        s4 = (const float4*)out0_b; d4 = (float4*)o0bS;
        for (int idx = tid; idx < 64; idx += TPB) d4[idx] = s4[idx];
        s4 = (const float4*)out1_b; d4 = (float4*)o1bS;
        for (int idx = tid; idx < 64; idx += TPB) d4[idx] = s4[idx];
        if (tid < 256) {
            float acc = 0.f;
            for (int i = 0; i < NL; ++i) acc += skip_b[i * 256 + tid];
            sbtS[tid] = acc;
        }
    }
    __syncthreads();
    if (tid < 64) {
        const int smp = seed[b];
        yb[0][tid] = ebt[smp * 64 + tid];   // x_0(t=0) = embed[seed]
        yb[1][tid] = 0.f;
        xl[0][tid] = 0.f;
        xl[1][tid] = 0.f;
        gb[0][tid] = 0.f;                   // avoid NaN*0 in layer-0 M-term
        gb[1][tid] = 0.f;
    }
    __syncthreads();

    WBc  CVa, CVb;
    WBrs RS;
    pf_cv(CVa, cvp, 0, tid);

    float* out_pred = out + (size_t)b * T;
    float* out_log  = out + (size_t)NB * T + (size_t)b * T * 256;

    const int p   = tid >> 4;          // conv/res column (0..63); second col p+64
    const int kk  = (tid & 15) * 4;    // conv/res K-chunk
    const int s   = tid >> 2;          // skip / head column (0..255)
    const int ks  = (tid & 3) * 16;    // skip K-chunk
    const int kb2 = (tid & 3) * 64;    // head K-chunk

    float skv = 0.f;

    for (int t = 0; t < T; ++t) {

        auto phase = [&](WBc& cur, WBc& nxt, const int i) {
            const int j = (i + 1 < NL) ? (i + 1) : 0;
            // ---- issue: ring read, RS_{i-1}, CV_j, ring push ----
            float xln = 0.f;
            if (w == 15) {
                const int dj = 1 << (j & 7);
                const int st = (i == NL - 1) ? (t + 1) : t;
                const int row = 255 * (j >> 3) + (dj - 1) + (st & (dj - 1));
                xln = __builtin_nontemporal_load(&q[(size_t)row * 64 + l]);
            }
            if (i) pf_rs(RS, rsp, i - 1, tid);
            pf_cv(nxt, cvp, j, tid);
            if (w == 14 && i) {             // push x_{i-1}(t) into layer-(i-1) ring row
                const int dp = 1 << ((i - 1) & 7);
                const int row = 255 * ((i - 1) >> 3) + (dp - 1) + (t & (dp - 1));
                __builtin_nontemporal_store(yb[(i - 1) & 1][l], &q[(size_t)row * 64 + l]);
            }
            const int ybi = i ? ((i - 1) & 1) : 0;   // buffer holding x_{i-1} (x_0 for i=0)
            const int gbi = (i - 1) & 1;             // buffer holding g_{i-1} (x*0 for i=0)
            // ---- 3-term conv (uses cur, loaded a full phase ago) ----
            const float4 xlv = *(const float4*)&xl[i & 1][kk];
            const float4 ypv = *(const float4*)&yb[ybi][kk];
            const float4 gpv = *(const float4*)&gb[gbi][kk];
            float4 aA = make_float4(0.f, 0.f, 0.f, 0.f);
            float4 aB = make_float4(0.f, 0.f, 0.f, 0.f);
            fma4(aA, xlv, cur.v[0]); fma4(aA, ypv, cur.v[2]); fma4(aA, gpv, cur.v[4]);
            fma4(aB, xlv, cur.v[1]); fma4(aB, ypv, cur.v[3]); fma4(aB, gpv, cur.v[5]);
            float hA = hadd4(aA), hB = hadd4(aB);
            hA += __shfl_xor(hA, 1);  hB += __shfl_xor(hB, 1);
            hA += __shfl_xor(hA, 2);  hB += __shfl_xor(hB, 2);
            hA += __shfl_xor(hA, 4);  hB += __shfl_xor(hB, 4);
            hA += __shfl_xor(hA, 8);  hB += __shfl_xor(hB, 8);
            hA += cb2S[i * 128 + p];
            hB += cb2S[i * 128 + 64 + p];
            const float g = tanhf(hA) * (1.f / (1.f + expf(-hB)));
            // ---- deferred res + skip of layer i-1 ----
            float ynew = 0.f;
            if (i) {
                float4 ra = make_float4(0.f, 0.f, 0.f, 0.f);
                fma4(ra, gpv, RS.v[0]);
                float racc = hadd4(ra);
                racc += __shfl_xor(racc, 1);
                racc += __shfl_xor(racc, 2);
                racc += __shfl_xor(racc, 4);
                racc += __shfl_xor(racc, 8);
                ynew = yb[ybi][p] + racc + rbS[(i - 1) * 64 + p];
                const float4 gs0 = *(const float4*)&gb[gbi][ks];
                const float4 gs1 = *(const float4*)&gb[gbi][ks + 4];
                const float4 gs2 = *(const float4*)&gb[gbi][ks + 8];
                const float4 gs3 = *(const float4*)&gb[gbi][ks + 12];
                float4 sa = make_float4(0.f, 0.f, 0.f, 0.f);
                fma4(sa, gs0, RS.v[1]); fma4(sa, gs1, RS.v[2]);
                fma4(sa, gs2, RS.v[3]); fma4(sa, gs3, RS.v[4]);
                float ss = hadd4(sa);
                ss += __shfl_xor(ss, 1);
                ss += __shfl_xor(ss, 2);
                skv += ss;
            }
            // ---- publish ----
            if ((tid & 15) == 0) {
                gb[i & 1][p] = g;
                if (i) yb[i & 1][p] = ynew;
            }
            if (w == 15) xl[j & 1][l] = xln;
            bar();
        };

#pragma unroll 1
        for (int ii = 0; ii < NL; ii += 2) {
            phase(CVa, CVb, ii);
            phase(CVb, CVa, ii + 1);
        }

        // ---------------- head A: skip_23, finalize skl, push row(23) ----------------
        {
            pf_rs(RS, rsp, NL - 1, tid);
            const float4 gs0 = *(const float4*)&gb[1][ks];
            const float4 gs1 = *(const float4*)&gb[1][ks + 4];
            const float4 gs2 = *(const float4*)&gb[1][ks + 8];
            const float4 gs3 = *(const float4*)&gb[1][ks + 12];
            float4 sa = make_float4(0.f, 0.f, 0.f, 0.f);
            fma4(sa, gs0, RS.v[1]); fma4(sa, gs1, RS.v[2]);
            fma4(sa, gs2, RS.v[3]); fma4(sa, gs3, RS.v[4]);
            float ss = hadd4(sa);
            ss += __shfl_xor(ss, 1);
            ss += __shfl_xor(ss, 2);
            skv += ss;
            if ((tid & 3) == 0) skl[s] = skv + sbtS[s];
            skv = 0.f;
            if (w == 14) {                  // push x_23(t) into layer-23 ring row
                const int row = 510 + 127 + (t & 127);
                __builtin_nontemporal_store(yb[1][l], &q[(size_t)row * 64 + l]);
            }
            bar();
        }
        // ---------------- head B: GEMV1 ----------------
        {
            const float4* hp = php + tid;
            float4 ha = make_float4(0.f, 0.f, 0.f, 0.f);
#pragma unroll
            for (int jj = 0; jj < 16; ++jj) {
                const float4 wv = hp[jj * 1024];
                const float4 sv = *(const float4*)&skl[kb2 + jj * 4];
                fma4(ha, sv, wv);
            }
            float hs = hadd4(ha);
            hs += __shfl_xor(hs, 1);
            hs += __shfl_xor(hs, 2);
            const float h0 = fmaxf(hs + o0bS[s], 0.f);
            if ((tid & 3) == 0) h0l[s] = h0;
        }
        bar();
        // ---------------- head C: GEMV2 + wave argmax ----------------
        {
            const float4* hp = php + (16 * 1024) + tid;
            float4 la = make_float4(0.f, 0.f, 0.f, 0.f);
#pragma unroll
            for (int jj = 0; jj < 16; ++jj) {
                const float4 wv = hp[jj * 1024];
                const float4 hv = *(const float4*)&h0l[kb2 + jj * 4];
                fma4(la, hv, wv);
            }
            float ls = hadd4(la);
            ls += __shfl_xor(ls, 1);
            ls += __shfl_xor(ls, 2);
            const float logit = ls + o1bS[s];
            if ((tid & 3) == 0)
                __builtin_nontemporal_store(logit, &out_log[(size_t)t * 256 + s]);
            float bv = logit; int bi = s;
#pragma unroll
            for (int off = 1; off <= 32; off <<= 1) {
                const float ov = __shfl_xor(bv, off);
                const int   oi = __shfl_xor(bi, off);
                if (ov > bv || (ov == bv && oi < bi)) { bv = ov; bi = oi; }
            }
            if (l == 0) { wmaxv[w] = bv; wmaxi[w] = bi; }
        }
        bar();
        // ---------------- head D: final argmax, x_0(t+1), mu-law ----------------
        {
            float fv = wmaxv[0]; int fi = wmaxi[0];
#pragma unroll
            for (int ww = 1; ww < 16; ++ww) {
                const float vv = wmaxv[ww]; const int vi = wmaxi[ww];
                if (vv > fv || (vv == fv && vi < fi)) { fv = vv; fi = vi; }
            }
            if (tid < 64) yb[0][tid] = ebt[fi * 64 + tid];   // x_0 of next step
            if (tid == 0) {
                const float mw = (float)fi * (2.0f / 255.0f) - 1.0f;
                const float a  = fabsf(mw);
                const float pp = (exp2f(8.0f * a) - 1.0f) * (1.0f / 255.0f);
                __builtin_nontemporal_store((mw < 0.f) ? -pp : pp, &out_pred[t]);
            }
        }
        bar();
    }
}

extern "C" void kernel_launch(void* const* d_in, const int* in_sizes, int n_in,
                              void* d_out, int out_size, void* d_ws, size_t ws_size,
                              hipStream_t stream) {
    const int*   seed   = (const int*)  d_in[0];
    const float* embed  = (const float*)d_in[1];
    const float* conv_k = (const float*)d_in[2];
    const float* conv_b = (const float*)d_in[3];
    const float* res_w  = (const float*)d_in[4];
    const float* res_b  = (const float*)d_in[5];
    const float* skip_w = (const float*)d_in[6];
    const float* skip_b = (const float*)d_in[7];
    const float* out0_w = (const float*)d_in[8];
    const float* out0_b = (const float*)d_in[9];
    const float* out1_w = (const float*)d_in[10];
    const float* out1_b = (const float*)d_in[11];
    const int*   Tptr   = (const int*)  d_in[12];

    float* ws = (float*)d_ws;
    float* ring = ws;
    const float4* cvp  = (const float4*)(ws + CV_OFF);
    const float4* rsp  = (const float4*)(ws + RS_OFF);
    const float4* php  = (const float4*)(ws + PH_OFF);
    const float*  cb2p = ws + CB2_OFF;

    repack1<<<dim3(NL), dim3(128), 0, stream>>>(conv_k, res_w, conv_b, res_b, ws);
    repack2<<<dim3(NL + 2), dim3(1024), 0, stream>>>(conv_k, res_w, skip_w, out0_w, out1_w, ws);

    wavenet_gen<<<dim3(NB), dim3(TPB), 0, stream>>>(
        seed, embed, res_b, skip_b, out0_b, out1_b, Tptr,
        (float*)d_out, ring, cvp, rsp, php, cb2p);
}